// Round 19
// baseline (245.018 us; speedup 1.0000x reference)
//
#include <hip/hip_runtime.h>

#define N_NODES 100000
#define N_EDGES 800000
#define DIM 128
#define OUTD 40
#define OUTP 48  // padded to 3x16 MFMA col-tiles
#define BN_EPS 1e-5f
#define SCAN_NB 98   // ceil(100000/1024)
#define NBKT 98      // dst buckets of 1024 nodes
#define BKT_CAP 12288  // per-bucket pair capacity

typedef __bf16 bf16x8_t __attribute__((ext_vector_type(8)));
typedef float f32x4_t __attribute__((ext_vector_type(4)));
typedef float f32x2_t __attribute__((ext_vector_type(2)));

__device__ __forceinline__ unsigned short f2bf(float f) {
    unsigned int u = __builtin_bit_cast(unsigned int, f);
    u = (u + 0x7FFF + ((u >> 16) & 1)) >> 16;
    return (unsigned short)u;
}
__device__ __forceinline__ float bf2f_u(unsigned int lo16) {
    return __builtin_bit_cast(float, lo16 << 16);
}

// ---------------- workspace zero ----------------

__global__ __launch_bounds__(256) void zero_ws_kernel(int* __restrict__ p) {
    p[blockIdx.x * 256 + threadIdx.x] = 0;  // 20 blocks x 256 = 5120 dwords = 20480 B
}

// ---------------- CSR build: bucketed (XCD-local writes) ----------------

__global__ __launch_bounds__(256) void bucketA_kernel(const int* __restrict__ src,
                                                      const int* __restrict__ dst,
                                                      uint2* __restrict__ pairs,
                                                      int* __restrict__ gcursor) {
    __shared__ int cnt[NBKT], base[NBKT], rec[NBKT];
    const int t = threadIdx.x;
    if (t < NBKT) { cnt[t] = 0; rec[t] = 0; }
    __syncthreads();
    const int e0 = blockIdx.x * 4096 + t * 16;
    const bool active = (e0 + 16 <= N_EDGES);  // tail is 80x16 -> all-or-nothing
    int s[16], d[16];
    if (active) {
#pragma unroll
        for (int i = 0; i < 4; ++i) {
            int4 sv = *reinterpret_cast<const int4*>(&src[e0 + i * 4]);
            int4 dv = *reinterpret_cast<const int4*>(&dst[e0 + i * 4]);
            s[i * 4 + 0] = sv.x; s[i * 4 + 1] = sv.y; s[i * 4 + 2] = sv.z; s[i * 4 + 3] = sv.w;
            d[i * 4 + 0] = dv.x; d[i * 4 + 1] = dv.y; d[i * 4 + 2] = dv.z; d[i * 4 + 3] = dv.w;
        }
#pragma unroll
        for (int i = 0; i < 16; ++i) atomicAdd(&cnt[d[i] >> 10], 1);
    }
    __syncthreads();
    if (t < NBKT && cnt[t] > 0) base[t] = atomicAdd(&gcursor[t], cnt[t]);
    __syncthreads();
    if (active) {
#pragma unroll
        for (int i = 0; i < 16; ++i) {
            int bk = d[i] >> 10;
            int loc = atomicAdd(&rec[bk], 1);
            pairs[(size_t)bk * BKT_CAP + base[bk] + loc] = make_uint2((unsigned)s[i], (unsigned)d[i]);
        }
    }
}

__global__ __launch_bounds__(256) void phaseB_deg_kernel(const uint2* __restrict__ pairs,
                                                         const int* __restrict__ gcursor,
                                                         int* __restrict__ deg) {
    __shared__ int hist[1024];
    const int b = blockIdx.x;
    const int t = threadIdx.x;
#pragma unroll
    for (int j = 0; j < 4; ++j) hist[t * 4 + j] = 0;
    __syncthreads();
    const int m = gcursor[b];
    const uint2* __restrict__ bp = &pairs[(size_t)b * BKT_CAP];
    for (int i = t; i < m; i += 256) {
        uint2 p = bp[i];
        atomicAdd(&hist[p.y & 1023], 1);
    }
    __syncthreads();
    const int n0 = b << 10;
#pragma unroll
    for (int j = 0; j < 4; ++j) {
        int node = n0 + t * 4 + j;
        if (node < N_NODES) deg[node] = hist[t * 4 + j];
    }
}

__global__ __launch_bounds__(256) void scan_partial_kernel(const int* __restrict__ deg,
                                                           int* __restrict__ partials) {
    int b = blockIdx.x;
    int tid = threadIdx.x;
    int base = b * 1024 + tid * 4;
    int t0 = 0, t1 = 0, t2 = 0, t3 = 0;
    if (base + 3 < N_NODES) {
        int4 v = *reinterpret_cast<const int4*>(&deg[base]);
        t0 = v.x; t1 = v.y; t2 = v.z; t3 = v.w;
    } else {
        if (base + 0 < N_NODES) t0 = deg[base + 0];
        if (base + 1 < N_NODES) t1 = deg[base + 1];
        if (base + 2 < N_NODES) t2 = deg[base + 2];
        if (base + 3 < N_NODES) t3 = deg[base + 3];
    }
    int s = t0 + t1 + t2 + t3;
    __shared__ int red[256];
    red[tid] = s;
    __syncthreads();
    for (int o = 128; o; o >>= 1) {
        if (tid < o) red[tid] += red[tid + o];
        __syncthreads();
    }
    if (tid == 0) partials[b] = red[0];
}

__global__ __launch_bounds__(128) void scan_partials_kernel(int* __restrict__ partials) {
    __shared__ int s[128];
    int t = threadIdx.x;
    int v = (t < SCAN_NB) ? partials[t] : 0;
    s[t] = v;
    __syncthreads();
    for (int off = 1; off < 128; off <<= 1) {
        int u = (t >= off) ? s[t - off] : 0;
        __syncthreads();
        s[t] += u;
        __syncthreads();
    }
    if (t < SCAN_NB) partials[t] = s[t] - v;  // exclusive
}

__global__ __launch_bounds__(256) void scan_final_kernel(const int* __restrict__ deg,
                                                         const int* __restrict__ partials,
                                                         int* __restrict__ row_off) {
    int b = blockIdx.x;
    int tid = threadIdx.x;
    int base = b * 1024 + tid * 4;
    int t0 = 0, t1 = 0, t2 = 0, t3 = 0;
    if (base + 3 < N_NODES) {
        int4 v = *reinterpret_cast<const int4*>(&deg[base]);
        t0 = v.x; t1 = v.y; t2 = v.z; t3 = v.w;
    } else {
        if (base + 0 < N_NODES) t0 = deg[base + 0];
        if (base + 1 < N_NODES) t1 = deg[base + 1];
        if (base + 2 < N_NODES) t2 = deg[base + 2];
        if (base + 3 < N_NODES) t3 = deg[base + 3];
    }
    int s = t0 + t1 + t2 + t3;
    __shared__ int sc[256];
    sc[tid] = s;
    __syncthreads();
    for (int off = 1; off < 256; off <<= 1) {
        int u = (tid >= off) ? sc[tid - off] : 0;
        __syncthreads();
        sc[tid] += u;
        __syncthreads();
    }
    int run = partials[b] + sc[tid] - s;
    if (base + 0 < N_NODES) row_off[base + 0] = run; run += t0;
    if (base + 1 < N_NODES) row_off[base + 1] = run; run += t1;
    if (base + 2 < N_NODES) row_off[base + 2] = run; run += t2;
    if (base + 3 < N_NODES) row_off[base + 3] = run;
    if (b == 0 && tid == 0) row_off[N_NODES] = N_EDGES;
}

__global__ __launch_bounds__(256) void phaseC_fill_kernel(const uint2* __restrict__ pairs,
                                                          const int* __restrict__ gcursor,
                                                          const int* __restrict__ row_off,
                                                          int* __restrict__ csr_src) {
    __shared__ int cur[1024];
    const int b = blockIdx.x;
    const int t = threadIdx.x;
    const int n0 = b << 10;
#pragma unroll
    for (int j = 0; j < 4; ++j) {
        int node = n0 + t * 4 + j;
        if (node < N_NODES) cur[t * 4 + j] = row_off[node];
    }
    __syncthreads();
    const int m = gcursor[b];
    const uint2* __restrict__ bp = &pairs[(size_t)b * BKT_CAP];
    for (int i = t; i < m; i += 256) {
        uint2 p = bp[i];
        int pos = atomicAdd(&cur[p.y & 1023], 1);
        csr_src[pos] = (int)p.x;
    }
}

// ---------------- fp32 -> bf16 convert (feat) ----------------

__global__ __launch_bounds__(256) void convert_bf16_kernel(const float* __restrict__ in,
                                                           unsigned short* __restrict__ out) {
    size_t i = (size_t)(blockIdx.x * blockDim.x + threadIdx.x) * 4;
    float4 v = *reinterpret_cast<const float4*>(&in[i]);
    ushort4 o;
    o.x = f2bf(v.x); o.y = f2bf(v.y); o.z = f2bf(v.z); o.w = f2bf(v.w);
    *reinterpret_cast<ushort4*>(&out[i]) = o;
}

// ---------------- weight transpose+convert: WT[n][k] = W[k][n], bf16 ----------------

__global__ __launch_bounds__(256) void wt_build_kernel(const float* __restrict__ Ws0,
                                                       const float* __restrict__ Wn0,
                                                       const float* __restrict__ Ws1,
                                                       const float* __restrict__ Wn1,
                                                       unsigned short* __restrict__ WT0,
                                                       unsigned short* __restrict__ WT1) {
    int e = blockIdx.x * blockDim.x + threadIdx.x;  // 0..65535
    int layer = e >> 15;
    int r = e & 32767;
    int n = r >> 8;
    int k = r & 255;
    const float* Ws = layer ? Ws1 : Ws0;
    const float* Wn = layer ? Wn1 : Wn0;
    float v = (k < DIM) ? Ws[k * DIM + n] : Wn[(k - DIM) * DIM + n];
    unsigned short* WT = layer ? WT1 : WT0;
    WT[n * 256 + k] = f2bf(v);
}

__global__ __launch_bounds__(256) void wt2_build_kernel(const float* __restrict__ Ws2,
                                                        const float* __restrict__ Wn2,
                                                        unsigned short* __restrict__ WT2) {
    int e = blockIdx.x * blockDim.x + threadIdx.x;  // 0..12287
    int n = e >> 8;
    int k = e & 255;
    float v = 0.f;
    if (n < OUTD) v = (k < DIM) ? Ws2[k * OUTD + n] : Wn2[(k - DIM) * OUTD + n];
    WT2[n * 256 + k] = f2bf(v);
}

// ---------------- BN prep: 8-replica reduce -> per-column scale/shift ----------------
// bnss[c] = gamma[c]*rsqrt(var+eps); bnss[128+c] = beta[c] - mean*scale.

__global__ __launch_bounds__(128) void bn_prep_kernel(const float* __restrict__ bnbuf,
                                                      const float* __restrict__ gamma,
                                                      const float* __restrict__ beta,
                                                      float* __restrict__ bnss) {
    const int t = threadIdx.x;  // 0..127
    float s = 0.f, q = 0.f;
#pragma unroll
    for (int r = 0; r < 8; ++r) {
        s += bnbuf[r * 256 + t];
        q += bnbuf[r * 256 + 128 + t];
    }
    const float invN = 1.0f / (float)N_NODES;
    float mean = s * invN;
    float var = q * invN - mean * mean;
    float sc = gamma[t] * rsqrtf(var + BN_EPS);
    bnss[t] = sc;
    bnss[128 + t] = beta[t] - mean * sc;
}

// ---------------- mean aggregation v8: fused optional BN+ReLU on gather ----------------
// 4 nodes per wave (16-lane group per node); 8 gathers in flight per group.
// If bnss != null, each gathered element y = max(x*scale + shift, 0).

__device__ __forceinline__ void unpack_add2(f32x2_t* a, uint4 v) {
    f32x2_t t0, t1, t2, t3;
    t0[0] = bf2f_u(v.x << 16 >> 16 << 16 >> 16);  // placeholder avoided below
    (void)t0; (void)t1; (void)t2; (void)t3;
    a[0][0] += bf2f_u(v.x & 0xFFFFu);
    a[0][1] += __builtin_bit_cast(float, v.x & 0xFFFF0000u);
    a[1][0] += bf2f_u(v.y & 0xFFFFu);
    a[1][1] += __builtin_bit_cast(float, v.y & 0xFFFF0000u);
    a[2][0] += bf2f_u(v.z & 0xFFFFu);
    a[2][1] += __builtin_bit_cast(float, v.z & 0xFFFF0000u);
    a[3][0] += bf2f_u(v.w & 0xFFFFu);
    a[3][1] += __builtin_bit_cast(float, v.w & 0xFFFF0000u);
}

__device__ __forceinline__ void unpack_bn_add2(f32x2_t* a, uint4 v,
                                               const float* s, const float* sh) {
    unsigned int w[4] = {v.x, v.y, v.z, v.w};
#pragma unroll
    for (int q = 0; q < 4; ++q) {
        float x0 = bf2f_u(w[q] & 0xFFFFu);
        float x1 = __builtin_bit_cast(float, w[q] & 0xFFFF0000u);
        float y0 = fmaxf(fmaf(x0, s[2 * q], sh[2 * q]), 0.f);
        float y1 = fmaxf(fmaf(x1, s[2 * q + 1], sh[2 * q + 1]), 0.f);
        a[q][0] += y0;
        a[q][1] += y1;
    }
}

__global__ __launch_bounds__(256) void agg_bf16_kernel(const unsigned short* __restrict__ h,
                                                       const int* __restrict__ row_off,
                                                       const int* __restrict__ csr_src,
                                                       unsigned short* __restrict__ hn,
                                                       const float* __restrict__ bnss) {
    const int wave = threadIdx.x >> 6;
    const int lane = threadIdx.x & 63;
    const int grp = lane >> 4;     // node-within-wave (group owns node)
    const int l16 = lane & 15;     // 16B slice of the 256B row
    const int node = blockIdx.x * 16 + wave * 4 + grp;  // 100000 = 6250*16, no tail
    const int lo = row_off[node];
    const int hi = row_off[node + 1];
    const int cnt = hi - lo;

    f32x2_t a2[4];
#pragma unroll
    for (int q = 0; q < 4; ++q) a2[q] = (f32x2_t){0.f, 0.f};
    const unsigned rowoff = (unsigned)l16 * 8u;

    if (bnss == nullptr) {
        for (int t = 0; t < cnt; t += 8) {
            const int last = cnt - 1;
            int idx[8];
            bool p[8];
#pragma unroll
            for (int j = 0; j < 8; ++j) {
                p[j] = (t + j < cnt);
                idx[j] = csr_src[lo + min(t + j, last)];
            }
            uint4 v[8];
#pragma unroll
            for (int j = 0; j < 8; ++j)
                v[j] = *reinterpret_cast<const uint4*>(&h[(size_t)idx[j] * DIM + rowoff]);
#pragma unroll
            for (int j = 0; j < 8; ++j)
                if (p[j]) unpack_add2(a2, v[j]);
        }
    } else {
        float s[8], sh[8];
#pragma unroll
        for (int j = 0; j < 8; ++j) {
            s[j] = bnss[l16 * 8 + j];
            sh[j] = bnss[128 + l16 * 8 + j];
        }
        for (int t = 0; t < cnt; t += 8) {
            const int last = cnt - 1;
            int idx[8];
            bool p[8];
#pragma unroll
            for (int j = 0; j < 8; ++j) {
                p[j] = (t + j < cnt);
                idx[j] = csr_src[lo + min(t + j, last)];
            }
            uint4 v[8];
#pragma unroll
            for (int j = 0; j < 8; ++j)
                v[j] = *reinterpret_cast<const uint4*>(&h[(size_t)idx[j] * DIM + rowoff]);
#pragma unroll
            for (int j = 0; j < 8; ++j)
                if (p[j]) unpack_bn_add2(a2, v[j], s, sh);
        }
    }

    const float rd = (cnt > 0) ? 1.0f / (float)cnt : 1.0f;
    uint4 o;
    o.x = (unsigned int)f2bf(a2[0][0] * rd) | ((unsigned int)f2bf(a2[0][1] * rd) << 16);
    o.y = (unsigned int)f2bf(a2[1][0] * rd) | ((unsigned int)f2bf(a2[1][1] * rd) << 16);
    o.z = (unsigned int)f2bf(a2[2][0] * rd) | ((unsigned int)f2bf(a2[2][1] * rd) << 16);
    o.w = (unsigned int)f2bf(a2[3][0] * rd) | ((unsigned int)f2bf(a2[3][1] * rd) << 16);
    *reinterpret_cast<uint4*>(&hn[(size_t)node * DIM + rowoff]) = o;
}

// ---------------- MFMA GEMM (32KB ks-split LDS) + optional A-side BN + 8-replica stats ----

__device__ __forceinline__ bf16x8_t bn_frag(bf16x8_t av, const float* __restrict__ bnss, int kk) {
    bf16x8_t r;
#pragma unroll
    for (int j = 0; j < 8; ++j) {
        float x = (float)av[j];
        float y = fmaxf(fmaf(x, bnss[kk + j], bnss[128 + kk + j]), 0.f);
        r[j] = (__bf16)y;
    }
    return r;
}

__global__ __launch_bounds__(256) void gemm_mfma_kernel(const unsigned short* __restrict__ Ab,
                                                        const unsigned short* __restrict__ Hb,
                                                        const unsigned short* __restrict__ WT,
                                                        unsigned short* __restrict__ C,
                                                        float* __restrict__ bnbuf,
                                                        const float* __restrict__ bnss) {
    __shared__ unsigned short wt[16384];  // 32 KB: one K-half [n=128][k=128], XOR-swizzled
    const int tid = threadIdx.x;
    const int wid = tid >> 6;
    const int lane = tid & 63;
    const int lrow = lane & 15;
    const int g = lane >> 4;
    const int r0 = blockIdx.x * 128 + wid * 32;

    bf16x8_t a[2][8];
#pragma unroll
    for (int ks = 0; ks < 8; ++ks) {
        const unsigned short* __restrict__ base = (ks < 4) ? Ab : Hb;
        const int kk = (ks & 3) * 32 + g * 8;
#pragma unroll
        for (int mt = 0; mt < 2; ++mt) {
            int row = r0 + mt * 16 + lrow;
            if (row >= N_NODES) row = N_NODES - 1;
            a[mt][ks] = *reinterpret_cast<const bf16x8_t*>(&base[(size_t)row * DIM + kk]);
        }
    }
    // A-side BN+ReLU (self path only: ks<4); Hb rows were BN'd by agg.
    if (bnss != nullptr) {
#pragma unroll
        for (int ks = 0; ks < 4; ++ks) {
            const int kk = ks * 32 + g * 8;
#pragma unroll
            for (int mt = 0; mt < 2; ++mt)
                a[mt][ks] = bn_frag(a[mt][ks], bnss, kk);
        }
    }

    f32x4_t acc[2][8];
#pragma unroll
    for (int mt = 0; mt < 2; ++mt)
#pragma unroll
        for (int nt = 0; nt < 8; ++nt) acc[mt][nt] = (f32x4_t){0.f, 0.f, 0.f, 0.f};

#pragma unroll
    for (int hh = 0; hh < 2; ++hh) {
        if (hh) __syncthreads();
#pragma unroll
        for (int i = 0; i < 8; ++i) {
            int c = i * 256 + tid;
            int n = c >> 4;
            int koff = (c & 15) * 8;
            unsigned int waddr = ((unsigned int)(c * 16)) ^ (((unsigned int)(n & 7)) << 4);
            uint4 v = *reinterpret_cast<const uint4*>(&WT[n * 256 + hh * 128 + koff]);
            *reinterpret_cast<uint4*>(reinterpret_cast<char*>(wt) + waddr) = v;
        }
        __syncthreads();
#pragma unroll
        for (int ks = 0; ks < 4; ++ks) {
#pragma unroll
            for (int nt = 0; nt < 8; ++nt) {
                int n = nt * 16 + lrow;
                unsigned int raddr = ((unsigned int)(n * 256 + ks * 64 + g * 16)) ^ (((unsigned int)(n & 7)) << 4);
                bf16x8_t b = *reinterpret_cast<const bf16x8_t*>(reinterpret_cast<const char*>(wt) + raddr);
                acc[0][nt] = __builtin_amdgcn_mfma_f32_16x16x32_bf16(a[0][hh * 4 + ks], b, acc[0][nt], 0, 0, 0);
                acc[1][nt] = __builtin_amdgcn_mfma_f32_16x16x32_bf16(a[1][hh * 4 + ks], b, acc[1][nt], 0, 0, 0);
            }
        }
    }

    float ssum[8], ssq[8];
#pragma unroll
    for (int nt = 0; nt < 8; ++nt) { ssum[nt] = 0.f; ssq[nt] = 0.f; }
#pragma unroll
    for (int mt = 0; mt < 2; ++mt) {
#pragma unroll
        for (int j = 0; j < 4; ++j) {
            int row = r0 + mt * 16 + g * 4 + j;
            if (row < N_NODES) {
#pragma unroll
                for (int nt = 0; nt < 8; ++nt) {
                    float v = acc[mt][nt][j];
                    ssum[nt] += v;
                    ssq[nt] += v * v;
                }
            }
        }
    }
#pragma unroll
    for (int nt = 0; nt < 8; ++nt) {
        ssum[nt] += __shfl_xor(ssum[nt], 16, 64);
        ssum[nt] += __shfl_xor(ssum[nt], 32, 64);
        ssq[nt] += __shfl_xor(ssq[nt], 16, 64);
        ssq[nt] += __shfl_xor(ssq[nt], 32, 64);
    }
    __syncthreads();
    float* ls = reinterpret_cast<float*>(wt);        // [4][128]
    float* lq = ls + 512;                            // [4][128]
    if (g == 0) {
#pragma unroll
        for (int nt = 0; nt < 8; ++nt) {
            ls[wid * 128 + nt * 16 + lrow] = ssum[nt];
            lq[wid * 128 + nt * 16 + lrow] = ssq[nt];
        }
    }
    __syncthreads();
    if (tid < 128) {
        float s = ls[tid] + ls[128 + tid] + ls[256 + tid] + ls[384 + tid];
        float q = lq[tid] + lq[128 + tid] + lq[256 + tid] + lq[384 + tid];
        float* rb = bnbuf + (blockIdx.x & 7) * 256;  // replica
        atomicAdd(&rb[tid], s);
        atomicAdd(&rb[128 + tid], q);
    }

#pragma unroll
    for (int mt = 0; mt < 2; ++mt) {
#pragma unroll
        for (int j = 0; j < 4; ++j) {
            int row = r0 + mt * 16 + g * 4 + j;
            if (row < N_NODES) {
#pragma unroll
                for (int nt = 0; nt < 8; ++nt)
                    C[(size_t)row * DIM + nt * 16 + lrow] = f2bf(acc[mt][nt][j]);
            }
        }
    }
}

// ---------------- output layer (MFMA): C[N][40] = [BN(A)|Hb] @ WT2^T + b ----------------

__global__ __launch_bounds__(256) void gemm_out_mfma_kernel(const unsigned short* __restrict__ Ab,
                                                            const unsigned short* __restrict__ Hb,
                                                            const unsigned short* __restrict__ WT2,
                                                            const float* __restrict__ bias,
                                                            float* __restrict__ C,
                                                            const float* __restrict__ bnss) {
    __shared__ unsigned short wt[OUTP * 256];  // 24 KB, XOR-swizzled
    const int tid = threadIdx.x;

#pragma unroll
    for (int i = 0; i < 6; ++i) {
        int c = i * 256 + tid;
        int n = c >> 5;
        unsigned int waddr = ((unsigned int)(c * 16)) ^ (((unsigned int)(n & 7)) << 4);
        uint4 v = *reinterpret_cast<const uint4*>(&WT2[c * 8]);
        *reinterpret_cast<uint4*>(reinterpret_cast<char*>(wt) + waddr) = v;
    }
    __syncthreads();

    const int wid = tid >> 6;
    const int lane = tid & 63;
    const int lrow = lane & 15;
    const int g = lane >> 4;
    const int r0 = blockIdx.x * 128 + wid * 32;

    bf16x8_t a[2][8];
#pragma unroll
    for (int ks = 0; ks < 8; ++ks) {
        const unsigned short* __restrict__ base = (ks < 4) ? Ab : Hb;
        const int kk = (ks & 3) * 32 + g * 8;
#pragma unroll
        for (int mt = 0; mt < 2; ++mt) {
            int row = r0 + mt * 16 + lrow;
            if (row >= N_NODES) row = N_NODES - 1;
            a[mt][ks] = *reinterpret_cast<const bf16x8_t*>(&base[(size_t)row * DIM + kk]);
        }
    }
    // A-side BN+ReLU (self path only)
#pragma unroll
    for (int ks = 0; ks < 4; ++ks) {
        const int kk = ks * 32 + g * 8;
#pragma unroll
        for (int mt = 0; mt < 2; ++mt)
            a[mt][ks] = bn_frag(a[mt][ks], bnss, kk);
    }

    f32x4_t acc[2][3];
#pragma unroll
    for (int mt = 0; mt < 2; ++mt)
#pragma unroll
        for (int nt = 0; nt < 3; ++nt) acc[mt][nt] = (f32x4_t){0.f, 0.f, 0.f, 0.f};

#pragma unroll
    for (int ks = 0; ks < 8; ++ks) {
#pragma unroll
        for (int nt = 0; nt < 3; ++nt) {
            int n = nt * 16 + lrow;
            unsigned int raddr = ((unsigned int)(n * 512 + ks * 64 + g * 16)) ^ (((unsigned int)(n & 7)) << 4);
            bf16x8_t b = *reinterpret_cast<const bf16x8_t*>(reinterpret_cast<const char*>(wt) + raddr);
            acc[0][nt] = __builtin_amdgcn_mfma_f32_16x16x32_bf16(a[0][ks], b, acc[0][nt], 0, 0, 0);
            acc[1][nt] = __builtin_amdgcn_mfma_f32_16x16x32_bf16(a[1][ks], b, acc[1][nt], 0, 0, 0);
        }
    }

    float bb[3];
#pragma unroll
    for (int nt = 0; nt < 3; ++nt) {
        int col = nt * 16 + lrow;
        bb[nt] = (col < OUTD) ? bias[col] : 0.f;
    }

#pragma unroll
    for (int mt = 0; mt < 2; ++mt) {
#pragma unroll
        for (int j = 0; j < 4; ++j) {
            int row = r0 + mt * 16 + g * 4 + j;
            if (row < N_NODES) {
#pragma unroll
                for (int nt = 0; nt < 3; ++nt) {
                    int col = nt * 16 + lrow;
                    if (col < OUTD)
                        C[(size_t)row * OUTD + col] = acc[mt][nt][j] + bb[nt];
                }
            }
        }
    }
}

// ---------------- launch ----------------

extern "C" void kernel_launch(void* const* d_in, const int* in_sizes, int n_in,
                              void* d_out, int out_size, void* d_ws, size_t ws_size,
                              hipStream_t stream) {
    const float* feat = (const float*)d_in[0];
    const int* src = (const int*)d_in[1];
    const int* dst = (const int*)d_in[2];
    const float* Ws0 = (const float*)d_in[3];
    const float* Wn0 = (const float*)d_in[4];
    const float* g0  = (const float*)d_in[5];
    const float* be0 = (const float*)d_in[6];
    const float* Ws1 = (const float*)d_in[7];
    const float* Wn1 = (const float*)d_in[8];
    const float* g1  = (const float*)d_in[9];
    const float* be1 = (const float*)d_in[10];
    const float* Ws2 = (const float*)d_in[11];
    const float* Wn2 = (const float*)d_in[12];
    const float* b2  = (const float*)d_in[13];
    float* out = (float*)d_out;

    // All large buffers explicitly 256B-aligned (round-14 lesson).
    char* ws = (char*)d_ws;
    int*   gcursor = (int*)(ws);                        //      0: 512 B  (zeroed)
    float* bn      = (float*)(ws + 4096);               //   4096: 16384 B (zeroed)
    int*   row_off = (int*)(ws + 20480);                //  20480: 400004 B
    int*   partials= (int*)(ws + 421120);               // 421120: 512 B
    uint2* pairs   = (uint2*)(ws + 421888);             // 9633792 B -> 10055680
    int*   csr     = (int*)(ws + 10055680);             // 3200000 B -> 13255680
    int*   deg     = (int*)(ws + 13255680);             // 400000 B -> 13655680
    unsigned short* featb = (unsigned short*)(ws + 13655808);  // 256-aligned; 25.6MB
    unsigned short* hnb   = (unsigned short*)(ws + 39255808);  // 25.6MB
    unsigned short* h0b   = (unsigned short*)(ws + 64855808);  // 25.6MB
    unsigned short* WT0   = (unsigned short*)(ws + 90455808);  // 65536
    unsigned short* WT1   = (unsigned short*)(ws + 90521344);  // 65536
    unsigned short* WT2   = (unsigned short*)(ws + 90586880);  // 24576 -> 90611456
    float* bn0ss   = (float*)(ws + 90611456);           // 1024 B
    float* bn1ss   = (float*)(ws + 90612480);           // 1024 B -> ends 90613504
    unsigned short* h1b   = featb;  // featb dead after layer-0 gemm
    float* bn0 = bn;           // layer-0 stats: 8 x 256
    float* bn1 = bn + 2048;    // layer-1 stats: 8 x 256

    const int ABK = (N_EDGES + 4095) / 4096;     // 196
    const int AGB = N_NODES / 16;                // 6250 (exact)
    const int MB = (N_NODES + 127) / 128;        // 782
    const int NE = (N_NODES * DIM) / 4 / 256;    // 12500

    zero_ws_kernel<<<20, 256, 0, stream>>>((int*)ws);  // zeros gcursor+bn stats

    bucketA_kernel<<<ABK, 256, 0, stream>>>(src, dst, pairs, gcursor);
    phaseB_deg_kernel<<<NBKT, 256, 0, stream>>>(pairs, gcursor, deg);
    scan_partial_kernel<<<SCAN_NB, 256, 0, stream>>>(deg, partials);
    scan_partials_kernel<<<1, 128, 0, stream>>>(partials);
    scan_final_kernel<<<SCAN_NB, 256, 0, stream>>>(deg, partials, row_off);
    phaseC_fill_kernel<<<NBKT, 256, 0, stream>>>(pairs, gcursor, row_off, csr);

    convert_bf16_kernel<<<NE, 256, 0, stream>>>(feat, featb);
    wt_build_kernel<<<256, 256, 0, stream>>>(Ws0, Wn0, Ws1, Wn1, WT0, WT1);
    wt2_build_kernel<<<48, 256, 0, stream>>>(Ws2, Wn2, WT2);

    // layer 0: inputs are raw features (no BN)
    agg_bf16_kernel<<<AGB, 256, 0, stream>>>(featb, row_off, csr, hnb, nullptr);
    gemm_mfma_kernel<<<MB, 256, 0, stream>>>(featb, hnb, WT0, h0b, bn0, nullptr);
    bn_prep_kernel<<<1, 128, 0, stream>>>(bn0, g0, be0, bn0ss);

    // layer 1: h0b is pre-BN; BN applied on the fly via bn0ss
    agg_bf16_kernel<<<AGB, 256, 0, stream>>>(h0b, row_off, csr, hnb, bn0ss);
    gemm_mfma_kernel<<<MB, 256, 0, stream>>>(h0b, hnb, WT1, h1b, bn1, bn0ss);
    bn_prep_kernel<<<1, 128, 0, stream>>>(bn1, g1, be1, bn1ss);

    // layer 2: h1b is pre-BN; BN applied on the fly via bn1ss
    agg_bf16_kernel<<<AGB, 256, 0, stream>>>(h1b, row_off, csr, hnb, bn1ss);
    gemm_out_mfma_kernel<<<MB, 256, 0, stream>>>(h1b, hnb, WT2, b2, out, bn1ss);
}

// Round 20
// 236.778 us; speedup vs baseline: 1.0348x; 1.0348x over previous
//
#include <hip/hip_runtime.h>

#define N_NODES 100000
#define N_EDGES 800000
#define DIM 128
#define OUTD 40
#define OUTP 48  // padded to 3x16 MFMA col-tiles
#define BN_EPS 1e-5f
#define SCAN_NB 98   // ceil(100000/1024)
#define NBKT 98      // dst buckets of 1024 nodes
#define BKT_CAP 12288  // per-bucket pair capacity

typedef __bf16 bf16x8_t __attribute__((ext_vector_type(8)));
typedef float f32x4_t __attribute__((ext_vector_type(4)));
typedef float f32x2_t __attribute__((ext_vector_type(2)));

__device__ __forceinline__ unsigned short f2bf(float f) {
    unsigned int u = __builtin_bit_cast(unsigned int, f);
    u = (u + 0x7FFF + ((u >> 16) & 1)) >> 16;
    return (unsigned short)u;
}

// ---------------- workspace zero ----------------

__global__ __launch_bounds__(256) void zero_ws_kernel(int* __restrict__ p) {
    p[blockIdx.x * 256 + threadIdx.x] = 0;  // 20 blocks x 256 = 5120 dwords = 20480 B
}

// ---------------- CSR build: bucketed (XCD-local writes) ----------------

__global__ __launch_bounds__(256) void bucketA_kernel(const int* __restrict__ src,
                                                      const int* __restrict__ dst,
                                                      uint2* __restrict__ pairs,
                                                      int* __restrict__ gcursor) {
    __shared__ int cnt[NBKT], base[NBKT], rec[NBKT];
    const int t = threadIdx.x;
    if (t < NBKT) { cnt[t] = 0; rec[t] = 0; }
    __syncthreads();
    const int e0 = blockIdx.x * 4096 + t * 16;
    const bool active = (e0 + 16 <= N_EDGES);  // tail is 80x16 -> all-or-nothing
    int s[16], d[16];
    if (active) {
#pragma unroll
        for (int i = 0; i < 4; ++i) {
            int4 sv = *reinterpret_cast<const int4*>(&src[e0 + i * 4]);
            int4 dv = *reinterpret_cast<const int4*>(&dst[e0 + i * 4]);
            s[i * 4 + 0] = sv.x; s[i * 4 + 1] = sv.y; s[i * 4 + 2] = sv.z; s[i * 4 + 3] = sv.w;
            d[i * 4 + 0] = dv.x; d[i * 4 + 1] = dv.y; d[i * 4 + 2] = dv.z; d[i * 4 + 3] = dv.w;
        }
#pragma unroll
        for (int i = 0; i < 16; ++i) atomicAdd(&cnt[d[i] >> 10], 1);
    }
    __syncthreads();
    if (t < NBKT && cnt[t] > 0) base[t] = atomicAdd(&gcursor[t], cnt[t]);
    __syncthreads();
    if (active) {
#pragma unroll
        for (int i = 0; i < 16; ++i) {
            int bk = d[i] >> 10;
            int loc = atomicAdd(&rec[bk], 1);
            pairs[(size_t)bk * BKT_CAP + base[bk] + loc] = make_uint2((unsigned)s[i], (unsigned)d[i]);
        }
    }
}

__global__ __launch_bounds__(256) void phaseB_deg_kernel(const uint2* __restrict__ pairs,
                                                         const int* __restrict__ gcursor,
                                                         int* __restrict__ deg) {
    __shared__ int hist[1024];
    const int b = blockIdx.x;
    const int t = threadIdx.x;
#pragma unroll
    for (int j = 0; j < 4; ++j) hist[t * 4 + j] = 0;
    __syncthreads();
    const int m = gcursor[b];
    const uint2* __restrict__ bp = &pairs[(size_t)b * BKT_CAP];
    for (int i = t; i < m; i += 256) {
        uint2 p = bp[i];
        atomicAdd(&hist[p.y & 1023], 1);
    }
    __syncthreads();
    const int n0 = b << 10;
#pragma unroll
    for (int j = 0; j < 4; ++j) {
        int node = n0 + t * 4 + j;
        if (node < N_NODES) deg[node] = hist[t * 4 + j];
    }
}

// exclusive scan of per-bucket edge counts (partials[b] == gcursor[b]:
// bucket b covers exactly nodes [b*1024,(b+1)*1024) == scan block b)
__global__ __launch_bounds__(128) void scan_partials_kernel(const int* __restrict__ gcursor,
                                                            int* __restrict__ partials) {
    __shared__ int s[128];
    int t = threadIdx.x;
    int v = (t < SCAN_NB) ? gcursor[t] : 0;
    s[t] = v;
    __syncthreads();
    for (int off = 1; off < 128; off <<= 1) {
        int u = (t >= off) ? s[t - off] : 0;
        __syncthreads();
        s[t] += u;
        __syncthreads();
    }
    if (t < SCAN_NB) partials[t] = s[t] - v;  // exclusive
}

__global__ __launch_bounds__(256) void scan_final_kernel(const int* __restrict__ deg,
                                                         const int* __restrict__ partials,
                                                         int* __restrict__ row_off) {
    int b = blockIdx.x;
    int tid = threadIdx.x;
    int base = b * 1024 + tid * 4;
    int t0 = 0, t1 = 0, t2 = 0, t3 = 0;
    if (base + 3 < N_NODES) {
        int4 v = *reinterpret_cast<const int4*>(&deg[base]);
        t0 = v.x; t1 = v.y; t2 = v.z; t3 = v.w;
    } else {
        if (base + 0 < N_NODES) t0 = deg[base + 0];
        if (base + 1 < N_NODES) t1 = deg[base + 1];
        if (base + 2 < N_NODES) t2 = deg[base + 2];
        if (base + 3 < N_NODES) t3 = deg[base + 3];
    }
    int s = t0 + t1 + t2 + t3;
    __shared__ int sc[256];
    sc[tid] = s;
    __syncthreads();
    for (int off = 1; off < 256; off <<= 1) {
        int u = (tid >= off) ? sc[tid - off] : 0;
        __syncthreads();
        sc[tid] += u;
        __syncthreads();
    }
    int run = partials[b] + sc[tid] - s;
    if (base + 0 < N_NODES) row_off[base + 0] = run; run += t0;
    if (base + 1 < N_NODES) row_off[base + 1] = run; run += t1;
    if (base + 2 < N_NODES) row_off[base + 2] = run; run += t2;
    if (base + 3 < N_NODES) row_off[base + 3] = run;
    if (b == 0 && tid == 0) row_off[N_NODES] = N_EDGES;
}

__global__ __launch_bounds__(256) void phaseC_fill_kernel(const uint2* __restrict__ pairs,
                                                          const int* __restrict__ gcursor,
                                                          const int* __restrict__ row_off,
                                                          int* __restrict__ csr_src) {
    __shared__ int cur[1024];
    const int b = blockIdx.x;
    const int t = threadIdx.x;
    const int n0 = b << 10;
#pragma unroll
    for (int j = 0; j < 4; ++j) {
        int node = n0 + t * 4 + j;
        if (node < N_NODES) cur[t * 4 + j] = row_off[node];
    }
    __syncthreads();
    const int m = gcursor[b];
    const uint2* __restrict__ bp = &pairs[(size_t)b * BKT_CAP];
    for (int i = t; i < m; i += 256) {
        uint2 p = bp[i];
        int pos = atomicAdd(&cur[p.y & 1023], 1);
        csr_src[pos] = (int)p.x;
    }
}

// ---------------- fp32 -> bf16 convert (feat) ----------------

__global__ __launch_bounds__(256) void convert_bf16_kernel(const float* __restrict__ in,
                                                           unsigned short* __restrict__ out) {
    size_t i = (size_t)(blockIdx.x * blockDim.x + threadIdx.x) * 4;
    float4 v = *reinterpret_cast<const float4*>(&in[i]);
    ushort4 o;
    o.x = f2bf(v.x); o.y = f2bf(v.y); o.z = f2bf(v.z); o.w = f2bf(v.w);
    *reinterpret_cast<ushort4*>(&out[i]) = o;
}

// ---------------- weight transpose+convert: WT[n][k] = W[k][n], bf16 ----------------

__global__ __launch_bounds__(256) void wt_build_kernel(const float* __restrict__ Ws0,
                                                       const float* __restrict__ Wn0,
                                                       const float* __restrict__ Ws1,
                                                       const float* __restrict__ Wn1,
                                                       unsigned short* __restrict__ WT0,
                                                       unsigned short* __restrict__ WT1) {
    int e = blockIdx.x * blockDim.x + threadIdx.x;  // 0..65535
    int layer = e >> 15;
    int r = e & 32767;
    int n = r >> 8;
    int k = r & 255;
    const float* Ws = layer ? Ws1 : Ws0;
    const float* Wn = layer ? Wn1 : Wn0;
    float v = (k < DIM) ? Ws[k * DIM + n] : Wn[(k - DIM) * DIM + n];
    unsigned short* WT = layer ? WT1 : WT0;
    WT[n * 256 + k] = f2bf(v);
}

__global__ __launch_bounds__(256) void wt2_build_kernel(const float* __restrict__ Ws2,
                                                        const float* __restrict__ Wn2,
                                                        unsigned short* __restrict__ WT2) {
    int e = blockIdx.x * blockDim.x + threadIdx.x;  // 0..12287
    int n = e >> 8;
    int k = e & 255;
    float v = 0.f;
    if (n < OUTD) v = (k < DIM) ? Ws2[k * OUTD + n] : Wn2[(k - DIM) * OUTD + n];
    WT2[n * 256 + k] = f2bf(v);
}

// ---------------- mean aggregation v7: node-per-16-lane-group, 8-deep MLP ----

__device__ __forceinline__ void unpack_add2(f32x2_t* a, uint4 v) {
    f32x2_t t0, t1, t2, t3;
    t0[0] = __builtin_bit_cast(float, v.x << 16);
    t0[1] = __builtin_bit_cast(float, v.x & 0xFFFF0000u);
    t1[0] = __builtin_bit_cast(float, v.y << 16);
    t1[1] = __builtin_bit_cast(float, v.y & 0xFFFF0000u);
    t2[0] = __builtin_bit_cast(float, v.z << 16);
    t2[1] = __builtin_bit_cast(float, v.z & 0xFFFF0000u);
    t3[0] = __builtin_bit_cast(float, v.w << 16);
    t3[1] = __builtin_bit_cast(float, v.w & 0xFFFF0000u);
    a[0] += t0;
    a[1] += t1;
    a[2] += t2;
    a[3] += t3;
}

__global__ __launch_bounds__(256) void agg_bf16_kernel(const unsigned short* __restrict__ h,
                                                       const int* __restrict__ row_off,
                                                       const int* __restrict__ csr_src,
                                                       unsigned short* __restrict__ hn) {
    const int wave = threadIdx.x >> 6;
    const int lane = threadIdx.x & 63;
    const int grp = lane >> 4;     // node-within-wave (group owns node)
    const int l16 = lane & 15;     // 16B slice of the 256B row
    const int node = blockIdx.x * 16 + wave * 4 + grp;  // 100000 = 6250*16, no tail
    const int lo = row_off[node];
    const int hi = row_off[node + 1];
    const int cnt = hi - lo;

    f32x2_t a2[4];
#pragma unroll
    for (int q = 0; q < 4; ++q) a2[q] = (f32x2_t){0.f, 0.f};
    const unsigned rowoff = (unsigned)l16 * 8u;

    for (int t = 0; t < cnt; t += 8) {  // group-uniform bound; groups diverge freely
        const int last = cnt - 1;
        int idx[8];
        bool p[8];
#pragma unroll
        for (int j = 0; j < 8; ++j) {
            p[j] = (t + j < cnt);
            idx[j] = csr_src[lo + min(t + j, last)];
        }
        uint4 v[8];
#pragma unroll
        for (int j = 0; j < 8; ++j)
            v[j] = *reinterpret_cast<const uint4*>(&h[(size_t)idx[j] * DIM + rowoff]);
#pragma unroll
        for (int j = 0; j < 8; ++j)
            if (p[j]) unpack_add2(a2, v[j]);
    }

    const float rd = (cnt > 0) ? 1.0f / (float)cnt : 1.0f;
    uint4 o;
    o.x = (unsigned int)f2bf(a2[0][0] * rd) | ((unsigned int)f2bf(a2[0][1] * rd) << 16);
    o.y = (unsigned int)f2bf(a2[1][0] * rd) | ((unsigned int)f2bf(a2[1][1] * rd) << 16);
    o.z = (unsigned int)f2bf(a2[2][0] * rd) | ((unsigned int)f2bf(a2[2][1] * rd) << 16);
    o.w = (unsigned int)f2bf(a2[3][0] * rd) | ((unsigned int)f2bf(a2[3][1] * rd) << 16);
    *reinterpret_cast<uint4*>(&hn[(size_t)node * DIM + rowoff]) = o;
}

// ---------------- MFMA GEMM (32KB ks-split LDS) + 8-replica BN stats ----------------

__global__ __launch_bounds__(256) void gemm_mfma_kernel(const unsigned short* __restrict__ Ab,
                                                        const unsigned short* __restrict__ Hb,
                                                        const unsigned short* __restrict__ WT,
                                                        unsigned short* __restrict__ C,
                                                        float* __restrict__ bnbuf) {
    __shared__ unsigned short wt[16384];  // 32 KB: one K-half [n=128][k=128], XOR-swizzled
    const int tid = threadIdx.x;
    const int wid = tid >> 6;
    const int lane = tid & 63;
    const int lrow = lane & 15;
    const int g = lane >> 4;
    const int r0 = blockIdx.x * 128 + wid * 32;

    bf16x8_t a[2][8];
#pragma unroll
    for (int ks = 0; ks < 8; ++ks) {
        const unsigned short* __restrict__ base = (ks < 4) ? Ab : Hb;
        const int kk = (ks & 3) * 32 + g * 8;
#pragma unroll
        for (int mt = 0; mt < 2; ++mt) {
            int row = r0 + mt * 16 + lrow;
            if (row >= N_NODES) row = N_NODES - 1;
            a[mt][ks] = *reinterpret_cast<const bf16x8_t*>(&base[(size_t)row * DIM + kk]);
        }
    }

    f32x4_t acc[2][8];
#pragma unroll
    for (int mt = 0; mt < 2; ++mt)
#pragma unroll
        for (int nt = 0; nt < 8; ++nt) acc[mt][nt] = (f32x4_t){0.f, 0.f, 0.f, 0.f};

#pragma unroll
    for (int hh = 0; hh < 2; ++hh) {
        if (hh) __syncthreads();
#pragma unroll
        for (int i = 0; i < 8; ++i) {
            int c = i * 256 + tid;
            int n = c >> 4;
            int koff = (c & 15) * 8;
            unsigned int waddr = ((unsigned int)(c * 16)) ^ (((unsigned int)(n & 7)) << 4);
            uint4 v = *reinterpret_cast<const uint4*>(&WT[n * 256 + hh * 128 + koff]);
            *reinterpret_cast<uint4*>(reinterpret_cast<char*>(wt) + waddr) = v;
        }
        __syncthreads();
#pragma unroll
        for (int ks = 0; ks < 4; ++ks) {
#pragma unroll
            for (int nt = 0; nt < 8; ++nt) {
                int n = nt * 16 + lrow;
                unsigned int raddr = ((unsigned int)(n * 256 + ks * 64 + g * 16)) ^ (((unsigned int)(n & 7)) << 4);
                bf16x8_t b = *reinterpret_cast<const bf16x8_t*>(reinterpret_cast<const char*>(wt) + raddr);
                acc[0][nt] = __builtin_amdgcn_mfma_f32_16x16x32_bf16(a[0][hh * 4 + ks], b, acc[0][nt], 0, 0, 0);
                acc[1][nt] = __builtin_amdgcn_mfma_f32_16x16x32_bf16(a[1][hh * 4 + ks], b, acc[1][nt], 0, 0, 0);
            }
        }
    }

    float ssum[8], ssq[8];
#pragma unroll
    for (int nt = 0; nt < 8; ++nt) { ssum[nt] = 0.f; ssq[nt] = 0.f; }
#pragma unroll
    for (int mt = 0; mt < 2; ++mt) {
#pragma unroll
        for (int j = 0; j < 4; ++j) {
            int row = r0 + mt * 16 + g * 4 + j;
            if (row < N_NODES) {
#pragma unroll
                for (int nt = 0; nt < 8; ++nt) {
                    float v = acc[mt][nt][j];
                    ssum[nt] += v;
                    ssq[nt] += v * v;
                }
            }
        }
    }
#pragma unroll
    for (int nt = 0; nt < 8; ++nt) {
        ssum[nt] += __shfl_xor(ssum[nt], 16, 64);
        ssum[nt] += __shfl_xor(ssum[nt], 32, 64);
        ssq[nt] += __shfl_xor(ssq[nt], 16, 64);
        ssq[nt] += __shfl_xor(ssq[nt], 32, 64);
    }
    __syncthreads();
    float* ls = reinterpret_cast<float*>(wt);        // [4][128]
    float* lq = ls + 512;                            // [4][128]
    if (g == 0) {
#pragma unroll
        for (int nt = 0; nt < 8; ++nt) {
            ls[wid * 128 + nt * 16 + lrow] = ssum[nt];
            lq[wid * 128 + nt * 16 + lrow] = ssq[nt];
        }
    }
    __syncthreads();
    if (tid < 128) {
        float s = ls[tid] + ls[128 + tid] + ls[256 + tid] + ls[384 + tid];
        float q = lq[tid] + lq[128 + tid] + lq[256 + tid] + lq[384 + tid];
        float* rb = bnbuf + (blockIdx.x & 7) * 256;  // replica
        atomicAdd(&rb[tid], s);
        atomicAdd(&rb[128 + tid], q);
    }

#pragma unroll
    for (int mt = 0; mt < 2; ++mt) {
#pragma unroll
        for (int j = 0; j < 4; ++j) {
            int row = r0 + mt * 16 + g * 4 + j;
            if (row < N_NODES) {
#pragma unroll
                for (int nt = 0; nt < 8; ++nt)
                    C[(size_t)row * DIM + nt * 16 + lrow] = f2bf(acc[mt][nt][j]);
            }
        }
    }
}

// ---------------- BatchNorm apply + ReLU, bf16 in-place (8-replica reduce) ----------------

__global__ __launch_bounds__(256) void bn_apply_bf16_kernel(unsigned short* __restrict__ H,
                                                            const float* __restrict__ bnbuf,
                                                            const float* __restrict__ gamma,
                                                            const float* __restrict__ beta) {
    __shared__ float red[256];  // [0..127]=col sums, [128..255]=col sumsq
    {
        int t = threadIdx.x;
        float s = 0.f;
#pragma unroll
        for (int r = 0; r < 8; ++r) s += bnbuf[r * 256 + t];
        red[t] = s;
    }
    __syncthreads();
    size_t idx = (size_t)(blockIdx.x * blockDim.x + threadIdx.x) * 8;
    const float invN = 1.0f / (float)N_NODES;
    int c = (int)(idx & (DIM - 1));
    uint4 v = *reinterpret_cast<const uint4*>(&H[idx]);
    unsigned int w[4] = {v.x, v.y, v.z, v.w};
    uint4 o;
    unsigned int* op = &o.x;
#pragma unroll
    for (int p = 0; p < 4; ++p) {
        float x0 = __builtin_bit_cast(float, w[p] << 16);
        float x1 = __builtin_bit_cast(float, w[p] & 0xFFFF0000u);
        int c0 = c + p * 2, c1 = c0 + 1;
        float mean0 = red[c0] * invN, mean1 = red[c1] * invN;
        float var0 = red[128 + c0] * invN - mean0 * mean0;
        float var1 = red[128 + c1] * invN - mean1 * mean1;
        float y0 = (x0 - mean0) * gamma[c0] * rsqrtf(var0 + BN_EPS) + beta[c0];
        float y1 = (x1 - mean1) * gamma[c1] * rsqrtf(var1 + BN_EPS) + beta[c1];
        y0 = y0 > 0.f ? y0 : 0.f;
        y1 = y1 > 0.f ? y1 : 0.f;
        op[p] = (unsigned int)f2bf(y0) | ((unsigned int)f2bf(y1) << 16);
    }
    *reinterpret_cast<uint4*>(&H[idx]) = o;
}

// ---------------- output layer (MFMA): C[N][40] = [Ab|Hb] @ WT2^T + b ----------------

__global__ __launch_bounds__(256) void gemm_out_mfma_kernel(const unsigned short* __restrict__ Ab,
                                                            const unsigned short* __restrict__ Hb,
                                                            const unsigned short* __restrict__ WT2,
                                                            const float* __restrict__ bias,
                                                            float* __restrict__ C) {
    __shared__ unsigned short wt[OUTP * 256];  // 24 KB, XOR-swizzled
    const int tid = threadIdx.x;

#pragma unroll
    for (int i = 0; i < 6; ++i) {
        int c = i * 256 + tid;
        int n = c >> 5;
        unsigned int waddr = ((unsigned int)(c * 16)) ^ (((unsigned int)(n & 7)) << 4);
        uint4 v = *reinterpret_cast<const uint4*>(&WT2[c * 8]);
        *reinterpret_cast<uint4*>(reinterpret_cast<char*>(wt) + waddr) = v;
    }
    __syncthreads();

    const int wid = tid >> 6;
    const int lane = tid & 63;
    const int lrow = lane & 15;
    const int g = lane >> 4;
    const int r0 = blockIdx.x * 128 + wid * 32;

    bf16x8_t a[2][8];
#pragma unroll
    for (int ks = 0; ks < 8; ++ks) {
        const unsigned short* __restrict__ base = (ks < 4) ? Ab : Hb;
        const int kk = (ks & 3) * 32 + g * 8;
#pragma unroll
        for (int mt = 0; mt < 2; ++mt) {
            int row = r0 + mt * 16 + lrow;
            if (row >= N_NODES) row = N_NODES - 1;
            a[mt][ks] = *reinterpret_cast<const bf16x8_t*>(&base[(size_t)row * DIM + kk]);
        }
    }

    f32x4_t acc[2][3];
#pragma unroll
    for (int mt = 0; mt < 2; ++mt)
#pragma unroll
        for (int nt = 0; nt < 3; ++nt) acc[mt][nt] = (f32x4_t){0.f, 0.f, 0.f, 0.f};

#pragma unroll
    for (int ks = 0; ks < 8; ++ks) {
#pragma unroll
        for (int nt = 0; nt < 3; ++nt) {
            int n = nt * 16 + lrow;
            unsigned int raddr = ((unsigned int)(n * 512 + ks * 64 + g * 16)) ^ (((unsigned int)(n & 7)) << 4);
            bf16x8_t b = *reinterpret_cast<const bf16x8_t*>(reinterpret_cast<const char*>(wt) + raddr);
            acc[0][nt] = __builtin_amdgcn_mfma_f32_16x16x32_bf16(a[0][ks], b, acc[0][nt], 0, 0, 0);
            acc[1][nt] = __builtin_amdgcn_mfma_f32_16x16x32_bf16(a[1][ks], b, acc[1][nt], 0, 0, 0);
        }
    }

    float bb[3];
#pragma unroll
    for (int nt = 0; nt < 3; ++nt) {
        int col = nt * 16 + lrow;
        bb[nt] = (col < OUTD) ? bias[col] : 0.f;
    }

#pragma unroll
    for (int mt = 0; mt < 2; ++mt) {
#pragma unroll
        for (int j = 0; j < 4; ++j) {
            int row = r0 + mt * 16 + g * 4 + j;
            if (row < N_NODES) {
#pragma unroll
                for (int nt = 0; nt < 3; ++nt) {
                    int col = nt * 16 + lrow;
                    if (col < OUTD)
                        C[(size_t)row * OUTD + col] = acc[mt][nt][j] + bb[nt];
                }
            }
        }
    }
}

// ---------------- launch ----------------

extern "C" void kernel_launch(void* const* d_in, const int* in_sizes, int n_in,
                              void* d_out, int out_size, void* d_ws, size_t ws_size,
                              hipStream_t stream) {
    const float* feat = (const float*)d_in[0];
    const int* src = (const int*)d_in[1];
    const int* dst = (const int*)d_in[2];
    const float* Ws0 = (const float*)d_in[3];
    const float* Wn0 = (const float*)d_in[4];
    const float* g0  = (const float*)d_in[5];
    const float* be0 = (const float*)d_in[6];
    const float* Ws1 = (const float*)d_in[7];
    const float* Wn1 = (const float*)d_in[8];
    const float* g1  = (const float*)d_in[9];
    const float* be1 = (const float*)d_in[10];
    const float* Ws2 = (const float*)d_in[11];
    const float* Wn2 = (const float*)d_in[12];
    const float* b2  = (const float*)d_in[13];
    float* out = (float*)d_out;

    // All large buffers explicitly 256B-aligned (round-14 lesson).
    char* ws = (char*)d_ws;
    int*   gcursor = (int*)(ws);                        //      0: 512 B  (zeroed)
    float* bn      = (float*)(ws + 4096);               //   4096: 16384 B (zeroed)
    int*   row_off = (int*)(ws + 20480);                //  20480: 400004 B
    int*   partials= (int*)(ws + 421120);               // 421120: 512 B
    uint2* pairs   = (uint2*)(ws + 421888);             // 9633792 B -> 10055680
    int*   csr     = (int*)(ws + 10055680);             // 3200000 B -> 13255680
    int*   deg     = (int*)(ws + 13255680);             // 400000 B -> 13655680
    unsigned short* featb = (unsigned short*)(ws + 13655808);  // 256-aligned; 25.6MB
    unsigned short* hnb   = (unsigned short*)(ws + 39255808);  // 25.6MB
    unsigned short* h0b   = (unsigned short*)(ws + 64855808);  // 25.6MB
    unsigned short* WT0   = (unsigned short*)(ws + 90455808);  // 65536
    unsigned short* WT1   = (unsigned short*)(ws + 90521344);  // 65536
    unsigned short* WT2   = (unsigned short*)(ws + 90586880);  // 24576
    unsigned short* h1b   = featb;  // featb dead after layer-0 gemm
    float* bn0 = bn;           // layer-0: 8 x 256
    float* bn1 = bn + 2048;    // layer-1: 8 x 256

    const int ABK = (N_EDGES + 4095) / 4096;     // 196
    const int AGB = N_NODES / 16;                // 6250 (exact)
    const int MB = (N_NODES + 127) / 128;        // 782
    const int NE = (N_NODES * DIM) / 4 / 256;    // 12500
    const int NB8 = (N_NODES * DIM) / 8 / 256;   // 6250

    zero_ws_kernel<<<20, 256, 0, stream>>>((int*)ws);  // zeros gcursor+bn (20480 B)

    bucketA_kernel<<<ABK, 256, 0, stream>>>(src, dst, pairs, gcursor);
    phaseB_deg_kernel<<<NBKT, 256, 0, stream>>>(pairs, gcursor, deg);
    scan_partials_kernel<<<1, 128, 0, stream>>>(gcursor, partials);  // partials[b]=excl-scan(gcursor)
    scan_final_kernel<<<SCAN_NB, 256, 0, stream>>>(deg, partials, row_off);
    phaseC_fill_kernel<<<NBKT, 256, 0, stream>>>(pairs, gcursor, row_off, csr);

    convert_bf16_kernel<<<NE, 256, 0, stream>>>(feat, featb);
    wt_build_kernel<<<256, 256, 0, stream>>>(Ws0, Wn0, Ws1, Wn1, WT0, WT1);
    wt2_build_kernel<<<48, 256, 0, stream>>>(Ws2, Wn2, WT2);

    // layer 0
    agg_bf16_kernel<<<AGB, 256, 0, stream>>>(featb, row_off, csr, hnb);
    gemm_mfma_kernel<<<MB, 256, 0, stream>>>(featb, hnb, WT0, h0b, bn0);
    bn_apply_bf16_kernel<<<NB8, 256, 0, stream>>>(h0b, bn0, g0, be0);

    // layer 1
    agg_bf16_kernel<<<AGB, 256, 0, stream>>>(h0b, row_off, csr, hnb);
    gemm_mfma_kernel<<<MB, 256, 0, stream>>>(h0b, hnb, WT1, h1b, bn1);
    bn_apply_bf16_kernel<<<NB8, 256, 0, stream>>>(h1b, bn1, g1, be1);

    // layer 2
    agg_bf16_kernel<<<AGB, 256, 0, stream>>>(h1b, row_off, csr, hnb);
    gemm_out_mfma_kernel<<<MB, 256, 0, stream>>>(h1b, hnb, WT2, b2, out);
}